// Round 11
// baseline (163.145 us; speedup 1.0000x reference)
//
#include <hip/hip_runtime.h>
#include <math.h>

// UpPolyAct: out = c0 + c1*x + 0.25*c2*( z_ee + V + W )
//   R = X M^T, L = M X, OO = L M^T
//   z_eo=(R+corr)^2, z_oe=(L+corr)^2, z_oo=OO^2, z_ee=(E X E)^2
//   U = z_oe + z_oo M,  V = M^T U,  W = z_eo M
//
// R11 = R10 + DS-pipe instruction-count reduction (NO math change).
// Diagnosis: R4(3blk)=44.8 ≈ R10(4blk)=45.5 despite occupancy change ->
// per-CU DS pipe saturated (~1440 DS-issue cyc/wave x 64 waves/CU ~ 38us
// of the 45.5us dispatch). Cuts (~-276 DS-cyc/wave, -19%):
//  - M2 vsrc: 32 broadcast b32 -> 8 f32x4 reads (chunked, static-indexed)
//  - P2 sRv reads: 16 b32 -> 4 f32x4 (jb%4==0, 16B-aligned)
//  - epilogue uvec: 16 b32 -> 4 f32x4
//  - ftab frags (gr,rb)/(g,rb) read ONCE into short8 regs, reused across
//    phases (C->P3, P4->P5), pinned via "+v" (R7-proven ext-vector tie)

typedef short short8 __attribute__((ext_vector_type(8)));
typedef float f32x16 __attribute__((ext_vector_type(16)));
typedef float f32x4 __attribute__((ext_vector_type(4)));

#define LSH 68  // bf16 LDS row stride (68 shorts = 136 B, rows 8B-aligned)

__device__ unsigned g_flag;                      // zero-initialized (.bss)
__device__ float g_gws[64];
__device__ __align__(16) short g_ftw[16 * 64 * 8];  // slot=(t*2+blk)*4+kk; t=0: [0,8KB), t=1: [8KB,16KB)

__device__ __forceinline__ short f2bf(float f) {
  unsigned u = __float_as_uint(f);
  u += 0x7FFFu + ((u >> 16) & 1u);
  return (short)(u >> 16);
}
__device__ __forceinline__ float bf2f(short s) {
  return __uint_as_float(((unsigned)(unsigned short)s) << 16);
}
__device__ __forceinline__ short8 ldrow(const short* p) {
  union { unsigned u[4]; short8 s; } v;
  const uint2 lo = *(const uint2*)p;
  const uint2 hi = *(const uint2*)(p + 4);
  v.u[0] = lo.x; v.u[1] = lo.y; v.u[2] = hi.x; v.u[3] = hi.y;
  return v.s;
}
__device__ __forceinline__ unsigned pk2(short a, short b) {
  return (unsigned)(unsigned short)a | ((unsigned)(unsigned short)b << 16);
}

// ---- setup: build g64 (64 f32) + ftab (16*64*8 bf16) into device globals ----
__global__ void uppolyact_setup() {
  if (g_flag == 0xC0FFEEu) return;  // replays early-out
  __shared__ float g64s[64];
  const int tid = threadIdx.x;
  if (tid < 64) {
    const int d = 2 * tid + 1;
    float s = 1.0f;
    for (int k = 1; k <= 32; ++k) {
      const int qq = (k * d) & 127;
      s += 2.0f * cosf((float)M_PI * (1.0f / 64.0f) * (float)qq);
    }
    const float gv = s * (1.0f / 64.0f);
    g64s[tid] = gv;
    g_gws[tid] = gv;
  }
  __syncthreads();
#pragma unroll
  for (int e = 0; e < 4; ++e) {
    const int entry = tid + 256 * e;  // 0..1023
    const int s_ = entry >> 6, ln = entry & 63;
    const int t_ = s_ >> 3, blk = (s_ >> 2) & 1, kk = s_ & 3;
    const int basei = kk * 16 + (ln >> 5) * 8 - (ln & 31) - 32 * blk;
    short* dst = &g_ftw[(s_ * 64 + ln) * 8];
#pragma unroll
    for (int j = 0; j < 8; ++j) {
      const int i0 = basei + j;
      const int idx = t_ ? ((-i0) & 63) : (i0 & 63);
      dst[j] = f2bf(g64s[idx]);
    }
  }
  __syncthreads();
  if (tid == 0) g_flag = 0xC0FFEEu;
}

__global__ __launch_bounds__(256, 4) void uppolyact_kernel(
    const float* __restrict__ x, const float* __restrict__ coef,
    float* __restrict__ out) {
  // bufA: X rows -> z_eo rows; bufB: X^T rows -> L rows -> U^T rows;
  // bufC: z_oo rows
  __shared__ __align__(16) short bufA[64 * LSH];
  __shared__ __align__(16) short bufB[64 * LSH];
  __shared__ __align__(16) short bufC[64 * LSH];
  __shared__ __align__(16) short ftab[8 * 64 * 8];  // time-shared: t=1 (gr) then t=0 (g)
  __shared__ __align__(16) float g64[64];
  __shared__ __align__(16) float tvec[64];
  __shared__ __align__(16) float uvec[64];
  __shared__ __align__(16) float sRv[64];
  __shared__ __align__(16) float Luv[64];
  __shared__ float sigv;

  const int tid = threadIdx.x;
  const int lane = tid & 63;
  const int w = tid >> 6;
  const int q = lane >> 5;
  const int l31 = lane & 31;
  const int rb = w >> 1, cb = w & 1;
  const int jcol = cb * 32 + l31;  // this thread's fixed output column
  const size_t base = (size_t)blockIdx.x * 4096;
  const float* xb = x + base;

  // ---- issue x loads FIRST (fragment order) ----
  float xcur[16];
#pragma unroll
  for (int r = 0; r < 16; ++r) {
    const int irow = rb * 32 + (r & 3) + 4 * q + 8 * (r >> 2);
    xcur[r] = xb[irow * 64 + jcol];
  }
  // ---- issue ftab t=1 (gr) copy loads: 8 KB, L2/L3-hot across all blocks
  f32x4 t0, t1;
  {
    const f32x4* fsrc = (const f32x4*)(g_ftw + 8 * 64 * 8);  // t=1 half
    t0 = fsrc[tid];
    t1 = fsrc[tid + 256];
  }
  if (tid < 64) g64[tid] = g_gws[tid];

  // ---- P0: xcur regs -> bufA (X rows, scalar) + bufB (X^T, packed b64) ----
#pragma unroll
  for (int k = 0; k < 4; ++k) {
    const int irowb = rb * 32 + 4 * q + 8 * k;  // irow = irowb + j, j=0..3
    short b[4];
#pragma unroll
    for (int j = 0; j < 4; ++j) {
      b[j] = f2bf(xcur[4 * k + j]);
      bufA[(irowb + j) * LSH + jcol] = b[j];
    }
    uint2 p;
    p.x = pk2(b[0], b[1]);
    p.y = pk2(b[2], b[3]);
    *(uint2*)&bufB[jcol * LSH + irowb] = p;
  }
  {
    f32x4* fdst = (f32x4*)ftab;
    fdst[tid] = t0;
    fdst[tid + 256] = t1;
  }
  __syncthreads();  // B1: g64 + bufA/bufB + ftab(t=1) published

  // ---- M1 tvec/uvec (all 256 threads, vectorized) ----
  {
    const int o = tid >> 1, h = tid & 1;  // o: output 0..127, h: half
    const short* src = (o < 64) ? &bufB[o * LSH + 32 * h]
                                : &bufA[(o - 64) * LSH + 32 * h];
    float acc = 0.0f;
#pragma unroll
    for (int p = 0; p < 4; ++p) {
      const short8 v = ldrow(src + 8 * p);
#pragma unroll
      for (int j = 0; j < 8; ++j) {
        const float f = bf2f(v[j]);
        acc += (j & 1) ? -f : f;
      }
    }
    acc += __shfl_xor(acc, 1);
    if (h == 0) {
      if (o < 64) tvec[o] = acc; else uvec[o - 64] = acc;
    }
  }
  __syncthreads();  // B2: tvec/uvec published

  // ---- Phase C: MFMA Rt, Lt + M2 sRv/Luv + sigv ----
  // fA = (gr,rb) fragments read ONCE; reused by P3's OOt (reg-carried).
  short8 fA[4];
#pragma unroll
  for (int kk = 0; kk < 4; ++kk) {
    fA[kk] = *(const short8*)&ftab[((rb * 4 + kk) * 64 + lane) * 8];
  }
  f32x16 Rt, Lt;
#pragma unroll
  for (int r = 0; r < 16; ++r) { Rt[r] = 0.0f; Lt[r] = 0.0f; }
#pragma unroll
  for (int kk = 0; kk < 4; ++kk) {
    const short8 bR = ldrow(&bufA[(cb * 32 + l31) * LSH + kk * 16 + q * 8]);
    Rt = __builtin_amdgcn_mfma_f32_32x32x16_bf16(fA[kk], bR, Rt, 0, 0, 0);
    const short8 aL = ldrow(&bufB[(rb * 32 + l31) * LSH + kk * 16 + q * 8]);
    const short8 bL = *(const short8*)&ftab[((cb * 4 + kk) * 64 + lane) * 8];  // (gr,cb)
    Lt = __builtin_amdgcn_mfma_f32_32x32x16_bf16(aL, bL, Lt, 0, 0, 0);
  }
#pragma unroll
  for (int kk = 0; kk < 4; ++kk) asm volatile("" : "+v"(fA[kk]));
  {
    // sRv[o]=sum_m tvec[m]*g64[(o-m)&63] ; Luv[o]=sum_m g64[(o-m)&63]*uvec[m]
    const int o = tid >> 1, h = tid & 1;
    const int o63 = o & 63;
    const float* vsrc = (o < 64) ? tvec : uvec;  // wave-uniform select
    const f32x4* vv = (const f32x4*)(vsrc + 32 * h);  // 16B-aligned
    float acc = 0.0f;
#pragma unroll
    for (int c = 0; c < 4; ++c) {
      const f32x4 a0 = vv[2 * c];
      const f32x4 a1 = vv[2 * c + 1];
#pragma unroll
      for (int j = 0; j < 8; ++j) {
        const int m = 32 * h + 8 * c + j;
        const float v = (j < 4) ? a0[j] : a1[j - 4];  // static after unroll
        acc += v * g64[(o63 - m) & 63];
      }
    }
    acc += __shfl_xor(acc, 1);
    if (h == 0) {
      if (o < 64) sRv[o] = acc; else Luv[o - 64] = acc;
    }
  }
  if (w == 0) {  // sigv = s^T X s
    float sv = (lane & 1) ? -tvec[lane] : tvec[lane];
#pragma unroll
    for (int d_ = 1; d_ < 64; d_ <<= 1) sv += __shfl_xor(sv, d_);
    if (lane == 0) sigv = sv;
  }
  __syncthreads();  // B3

  // ---- P2: issue ftab t=0 loads; z_eoT -> bufA, Lt -> bufB (packed) ----
  f32x4 u0, u1;
  {
    const f32x4* fsrc = (const f32x4*)g_ftw;  // t=0 half
    u0 = fsrc[tid];
    u1 = fsrc[tid + 256];
  }
  float zoe[16];
  {
    const int icol = cb * 32 + l31;
    const float sgi = (icol & 1) ? -1.0f : 1.0f;
    const float lu = Luv[icol];
#pragma unroll
    for (int k = 0; k < 4; ++k) {
      const int jb = rb * 32 + 4 * q + 8 * k;  // jb%4==0
      const f32x4 sr = *(const f32x4*)&sRv[jb];  // 4 consecutive sRv, one b128
      short ze[4], zl[4];
#pragma unroll
      for (int t = 0; t < 4; ++t) {
        const int r = 4 * k + t;
        const int jrow = jb + t;
        const float sgj = (jrow & 1) ? -1.0f : 1.0f;
        const float veo = Rt[r] + sgi * sr[t] * (1.0f / 64.0f);
        ze[t] = f2bf(veo * veo);               // z_eo[i][j]
        zl[t] = f2bf(Lt[r]);                   // L[i][j]
        const float voe = Lt[r] + lu * sgj * (1.0f / 64.0f);
        zoe[r] = voe * voe;                    // z_oeT[j][i] (C-layout)
      }
      uint2 pz, pl;
      pz.x = pk2(ze[0], ze[1]); pz.y = pk2(ze[2], ze[3]);
      pl.x = pk2(zl[0], zl[1]); pl.y = pk2(zl[2], zl[3]);
      *(uint2*)&bufA[icol * LSH + jb] = pz;
      *(uint2*)&bufB[icol * LSH + jb] = pl;
    }
  }
  __syncthreads();  // B4

  // ---- P3: OOt = M*Lt (fA regs, bufB=L) ; z_oo -> bufC (packed) ----
  f32x16 OOt;
#pragma unroll
  for (int r = 0; r < 16; ++r) OOt[r] = 0.0f;
#pragma unroll
  for (int kk = 0; kk < 4; ++kk) {
    const short8 b = ldrow(&bufB[(cb * 32 + l31) * LSH + kk * 16 + q * 8]);
    OOt = __builtin_amdgcn_mfma_f32_32x32x16_bf16(fA[kk], b, OOt, 0, 0, 0);
  }
  {
    const int icol = cb * 32 + l31;
#pragma unroll
    for (int k = 0; k < 4; ++k) {
      const int jb = rb * 32 + 4 * q + 8 * k;
      short zo[4];
#pragma unroll
      for (int t = 0; t < 4; ++t) {
        const int r = 4 * k + t;
        zo[t] = f2bf(OOt[r] * OOt[r]);
      }
      uint2 p;
      p.x = pk2(zo[0], zo[1]); p.y = pk2(zo[2], zo[3]);
      *(uint2*)&bufC[icol * LSH + jb] = p;  // z_oo[i][j]
    }
  }
  // pin: t=0 staging values materialized here (P2+P3 covered the L2 latency)
  asm volatile("" : "+v"(u0), "+v"(u1));
  __syncthreads();  // B5: all ftab t=1 reads done

  // ---- swap ftab to t=0 half ----
  {
    f32x4* fdst = (f32x4*)ftab;
    fdst[tid] = u0;
    fdst[tid + 256] = u1;
  }
  __syncthreads();  // B5b: ftab(t=0) published

  // ---- P4: Ut = z_oeT + M^T z_ooT ; W = z_eo*M ; U^T -> bufB ----
  // fU = (g,rb) fragments read ONCE; reused by P5's Vv (reg-carried).
  short8 fU[4];
#pragma unroll
  for (int kk = 0; kk < 4; ++kk) {
    fU[kk] = *(const short8*)&ftab[((rb * 4 + kk) * 64 + lane) * 8];
  }
  f32x16 Ut, Wv;
#pragma unroll
  for (int r = 0; r < 16; ++r) { Ut[r] = zoe[r]; Wv[r] = 0.0f; }
#pragma unroll
  for (int kk = 0; kk < 4; ++kk) {
    const short8 bU = ldrow(&bufC[(cb * 32 + l31) * LSH + kk * 16 + q * 8]);
    Ut = __builtin_amdgcn_mfma_f32_32x32x16_bf16(fU[kk], bU, Ut, 0, 0, 0);
    const short8 aW = ldrow(&bufA[(rb * 32 + l31) * LSH + kk * 16 + q * 8]);  // z_eo rows
    const short8 bW = *(const short8*)&ftab[((cb * 4 + kk) * 64 + lane) * 8];  // (g,cb)
    Wv = __builtin_amdgcn_mfma_f32_32x32x16_bf16(aW, bW, Wv, 0, 0, 0);
  }
#pragma unroll
  for (int kk = 0; kk < 4; ++kk) asm volatile("" : "+v"(fU[kk]));
#pragma unroll
  for (int r = 0; r < 16; ++r) {
    const int jrow = rb * 32 + (r & 3) + 4 * q + 8 * (r >> 2);
    const int icol = cb * 32 + l31;
    bufB[jrow * LSH + icol] = f2bf(Ut[r]);  // U^T row-major; strided, scalar
  }
  __syncthreads();  // B6

  // ---- P5: V = M^T U (fU regs) ; epilogue ----
  f32x16 Vv;
#pragma unroll
  for (int r = 0; r < 16; ++r) Vv[r] = 0.0f;
#pragma unroll
  for (int kk = 0; kk < 4; ++kk) {
    const short8 b = ldrow(&bufB[(cb * 32 + l31) * LSH + kk * 16 + q * 8]);
    Vv = __builtin_amdgcn_mfma_f32_32x32x16_bf16(fU[kk], b, Vv, 0, 0, 0);
  }

  const float c0 = coef[0], c1 = coef[1];
  const float c2q = 0.25f * coef[2];
  float* ob = out + base;
  const float tv = tvec[jcol];
  const float sgj = (jcol & 1) ? -1.0f : 1.0f;
  const float sg = sigv;
#pragma unroll
  for (int k = 0; k < 4; ++k) {
    const int irowb = rb * 32 + 4 * q + 8 * k;  // irowb%4==0, even
    const f32x4 uv = *(const f32x4*)&uvec[irowb];  // one b128 for 4 rows
#pragma unroll
    for (int j = 0; j < 4; ++j) {
      const int r = 4 * k + j;
      const int irow = irowb + j;
      const float sgi = (j & 1) ? -1.0f : 1.0f;  // irowb even -> parity = j&1
      const float xv_ = bf2f(f2bf(xcur[r]));
      const float vee = xv_ + (sgi * tv + uv[j] * sgj) * (1.0f / 64.0f) +
                        sgi * sgj * sg * (1.0f / 4096.0f);
      const float zee = vee * vee;
      ob[irow * 64 + jcol] = c0 + c1 * xcur[r] + c2q * (zee + Vv[r] + Wv[r]);
    }
  }
}

extern "C" void kernel_launch(void* const* d_in, const int* in_sizes, int n_in,
                              void* d_out, int out_size, void* d_ws,
                              size_t ws_size, hipStream_t stream) {
  const float* x = (const float*)d_in[0];
  const float* coef = (const float*)d_in[1];
  float* out = (float*)d_out;
  const int channels = out_size / 4096;  // 32*128 channels of 64x64
  uppolyact_setup<<<dim3(1), dim3(256), 0, stream>>>();
  uppolyact_kernel<<<dim3(channels), dim3(256), 0, stream>>>(x, coef, out);
}

// Round 12
// 156.808 us; speedup vs baseline: 1.0404x; 1.0404x over previous
//
#include <hip/hip_runtime.h>
#include <math.h>

// UpPolyAct: out = c0 + c1*x + 0.25*c2*( z_ee + V + W )
//   R = X M^T, L = M X, OO = L M^T
//   z_eo=(R+corr)^2, z_oe=(L+corr)^2, z_oo=OO^2, z_ee=(E X E)^2
//   U = z_oe + z_oo M,  V = M^T U,  W = z_eo M
//
// R12 = R10 + ONLY the zero-live-range DS-issue cuts (R11 post-mortem:
// its 79.5us regression was scratch spill — FETCH+52MB/WRITE+106MB — from
// the long-lived fragment pins + chunked M2 rewrite; compiler pins VGPR=64
// and spills rather than widening). Changes vs R10:
//  - P2: 16x sRv b32 -> 4x aligned f32x4 (jb%4==0, static extracts);
//        Luv[icol] hoisted to 1 read (was 16)
//  - epilogue: 16x uvec b32 -> 4x aligned f32x4; tvec[jcol], sigv hoisted
// No pins, no cross-barrier register lifetimes, M1/M2 untouched.

typedef short short8 __attribute__((ext_vector_type(8)));
typedef float f32x16 __attribute__((ext_vector_type(16)));
typedef float f32x4 __attribute__((ext_vector_type(4)));

#define LSH 68  // bf16 LDS row stride (68 shorts = 136 B, rows 8B-aligned)

__device__ unsigned g_flag;                      // zero-initialized (.bss)
__device__ float g_gws[64];
__device__ __align__(16) short g_ftw[16 * 64 * 8];  // slot=(t*2+blk)*4+kk; t=0: [0,8KB), t=1: [8KB,16KB)

__device__ __forceinline__ short f2bf(float f) {
  unsigned u = __float_as_uint(f);
  u += 0x7FFFu + ((u >> 16) & 1u);
  return (short)(u >> 16);
}
__device__ __forceinline__ float bf2f(short s) {
  return __uint_as_float(((unsigned)(unsigned short)s) << 16);
}
__device__ __forceinline__ short8 ldrow(const short* p) {
  union { unsigned u[4]; short8 s; } v;
  const uint2 lo = *(const uint2*)p;
  const uint2 hi = *(const uint2*)(p + 4);
  v.u[0] = lo.x; v.u[1] = lo.y; v.u[2] = hi.x; v.u[3] = hi.y;
  return v.s;
}
__device__ __forceinline__ unsigned pk2(short a, short b) {
  return (unsigned)(unsigned short)a | ((unsigned)(unsigned short)b << 16);
}

// ---- setup: build g64 (64 f32) + ftab (16*64*8 bf16) into device globals ----
__global__ void uppolyact_setup() {
  if (g_flag == 0xC0FFEEu) return;  // replays early-out
  __shared__ float g64s[64];
  const int tid = threadIdx.x;
  if (tid < 64) {
    const int d = 2 * tid + 1;
    float s = 1.0f;
    for (int k = 1; k <= 32; ++k) {
      const int qq = (k * d) & 127;
      s += 2.0f * cosf((float)M_PI * (1.0f / 64.0f) * (float)qq);
    }
    const float gv = s * (1.0f / 64.0f);
    g64s[tid] = gv;
    g_gws[tid] = gv;
  }
  __syncthreads();
#pragma unroll
  for (int e = 0; e < 4; ++e) {
    const int entry = tid + 256 * e;  // 0..1023
    const int s_ = entry >> 6, ln = entry & 63;
    const int t_ = s_ >> 3, blk = (s_ >> 2) & 1, kk = s_ & 3;
    const int basei = kk * 16 + (ln >> 5) * 8 - (ln & 31) - 32 * blk;
    short* dst = &g_ftw[(s_ * 64 + ln) * 8];
#pragma unroll
    for (int j = 0; j < 8; ++j) {
      const int i0 = basei + j;
      const int idx = t_ ? ((-i0) & 63) : (i0 & 63);
      dst[j] = f2bf(g64s[idx]);
    }
  }
  __syncthreads();
  if (tid == 0) g_flag = 0xC0FFEEu;
}

__global__ __launch_bounds__(256, 4) void uppolyact_kernel(
    const float* __restrict__ x, const float* __restrict__ coef,
    float* __restrict__ out) {
  // bufA: X rows -> z_eo rows; bufB: X^T rows -> L rows -> U^T rows;
  // bufC: z_oo rows
  __shared__ __align__(16) short bufA[64 * LSH];
  __shared__ __align__(16) short bufB[64 * LSH];
  __shared__ __align__(16) short bufC[64 * LSH];
  __shared__ __align__(16) short ftab[8 * 64 * 8];  // time-shared: t=1 (gr) then t=0 (g)
  __shared__ __align__(16) float g64[64];
  __shared__ __align__(16) float tvec[64];
  __shared__ __align__(16) float uvec[64];
  __shared__ __align__(16) float sRv[64];
  __shared__ __align__(16) float Luv[64];
  __shared__ float sigv;

  const int tid = threadIdx.x;
  const int lane = tid & 63;
  const int w = tid >> 6;
  const int q = lane >> 5;
  const int l31 = lane & 31;
  const int rb = w >> 1, cb = w & 1;
  const int jcol = cb * 32 + l31;  // this thread's fixed output column
  const size_t base = (size_t)blockIdx.x * 4096;
  const float* xb = x + base;

  // ---- issue x loads FIRST (fragment order) ----
  float xcur[16];
#pragma unroll
  for (int r = 0; r < 16; ++r) {
    const int irow = rb * 32 + (r & 3) + 4 * q + 8 * (r >> 2);
    xcur[r] = xb[irow * 64 + jcol];
  }
  // ---- issue ftab t=1 (gr) copy loads: 8 KB, L2/L3-hot across all blocks
  f32x4 t0, t1;
  {
    const f32x4* fsrc = (const f32x4*)(g_ftw + 8 * 64 * 8);  // t=1 half
    t0 = fsrc[tid];
    t1 = fsrc[tid + 256];
  }
  if (tid < 64) g64[tid] = g_gws[tid];

  // ---- P0: xcur regs -> bufA (X rows, scalar) + bufB (X^T, packed b64) ----
#pragma unroll
  for (int k = 0; k < 4; ++k) {
    const int irowb = rb * 32 + 4 * q + 8 * k;  // irow = irowb + j, j=0..3
    short b[4];
#pragma unroll
    for (int j = 0; j < 4; ++j) {
      b[j] = f2bf(xcur[4 * k + j]);
      bufA[(irowb + j) * LSH + jcol] = b[j];
    }
    uint2 p;
    p.x = pk2(b[0], b[1]);
    p.y = pk2(b[2], b[3]);
    *(uint2*)&bufB[jcol * LSH + irowb] = p;
  }
  {
    f32x4* fdst = (f32x4*)ftab;
    fdst[tid] = t0;
    fdst[tid + 256] = t1;
  }
  __syncthreads();  // B1: g64 + bufA/bufB + ftab(t=1) published

  // ---- M1 tvec/uvec (all 256 threads, vectorized) ----
  {
    const int o = tid >> 1, h = tid & 1;  // o: output 0..127, h: half
    const short* src = (o < 64) ? &bufB[o * LSH + 32 * h]
                                : &bufA[(o - 64) * LSH + 32 * h];
    float acc = 0.0f;
#pragma unroll
    for (int p = 0; p < 4; ++p) {
      const short8 v = ldrow(src + 8 * p);
#pragma unroll
      for (int j = 0; j < 8; ++j) {
        const float f = bf2f(v[j]);
        acc += (j & 1) ? -f : f;
      }
    }
    acc += __shfl_xor(acc, 1);
    if (h == 0) {
      if (o < 64) tvec[o] = acc; else uvec[o - 64] = acc;
    }
  }
  __syncthreads();  // B2: tvec/uvec published

  // ---- Phase C: MFMA Rt, Lt (frags from ftab t=1) + M2 sRv/Luv + sigv ----
  f32x16 Rt, Lt;
#pragma unroll
  for (int r = 0; r < 16; ++r) { Rt[r] = 0.0f; Lt[r] = 0.0f; }
#pragma unroll
  for (int kk = 0; kk < 4; ++kk) {
    const short8 aR = *(const short8*)&ftab[((rb * 4 + kk) * 64 + lane) * 8];  // (gr,rb)
    const short8 bR = ldrow(&bufA[(cb * 32 + l31) * LSH + kk * 16 + q * 8]);
    Rt = __builtin_amdgcn_mfma_f32_32x32x16_bf16(aR, bR, Rt, 0, 0, 0);
    const short8 aL = ldrow(&bufB[(rb * 32 + l31) * LSH + kk * 16 + q * 8]);
    const short8 bL = *(const short8*)&ftab[((cb * 4 + kk) * 64 + lane) * 8];  // (gr,cb)
    Lt = __builtin_amdgcn_mfma_f32_32x32x16_bf16(aL, bL, Lt, 0, 0, 0);
  }
  {
    // sRv[o]=sum_m tvec[m]*g64[(o-m)&63] ; Luv[o]=sum_m g64[(o-m)&63]*uvec[m]
    const int o = tid >> 1, h = tid & 1;
    const int o63 = o & 63;
    const float* vsrc = (o < 64) ? tvec : uvec;  // wave-uniform select
    float acc = 0.0f;
#pragma unroll
    for (int p = 0; p < 32; ++p) {
      const int m = 32 * h + p;
      acc += vsrc[m] * g64[(o63 - m) & 63];
    }
    acc += __shfl_xor(acc, 1);
    if (h == 0) {
      if (o < 64) sRv[o] = acc; else Luv[o - 64] = acc;
    }
  }
  if (w == 0) {  // sigv = s^T X s
    float sv = (lane & 1) ? -tvec[lane] : tvec[lane];
#pragma unroll
    for (int d_ = 1; d_ < 64; d_ <<= 1) sv += __shfl_xor(sv, d_);
    if (lane == 0) sigv = sv;
  }
  __syncthreads();  // B3

  // ---- P2: issue ftab t=0 loads; z_eoT -> bufA, Lt -> bufB (packed) ----
  f32x4 u0, u1;
  {
    const f32x4* fsrc = (const f32x4*)g_ftw;  // t=0 half
    u0 = fsrc[tid];
    u1 = fsrc[tid + 256];
  }
  float zoe[16];
  {
    const int icol = cb * 32 + l31;
    const float sgi = (icol & 1) ? -1.0f : 1.0f;
    const float lu = Luv[icol];  // hoisted: 1 read (was 16)
#pragma unroll
    for (int k = 0; k < 4; ++k) {
      const int jb = rb * 32 + 4 * q + 8 * k;  // jb%4==0 -> 16B-aligned
      const f32x4 sr = *(const f32x4*)&sRv[jb];  // 4 sRv in one b128
      short ze[4], zl[4];
#pragma unroll
      for (int t = 0; t < 4; ++t) {
        const int r = 4 * k + t;
        const int jrow = jb + t;
        const float sgj = (jrow & 1) ? -1.0f : 1.0f;
        const float veo = Rt[r] + sgi * sr[t] * (1.0f / 64.0f);
        ze[t] = f2bf(veo * veo);               // z_eo[i][j]
        zl[t] = f2bf(Lt[r]);                   // L[i][j]
        const float voe = Lt[r] + lu * sgj * (1.0f / 64.0f);
        zoe[r] = voe * voe;                    // z_oeT[j][i] (C-layout)
      }
      uint2 pz, pl;
      pz.x = pk2(ze[0], ze[1]); pz.y = pk2(ze[2], ze[3]);
      pl.x = pk2(zl[0], zl[1]); pl.y = pk2(zl[2], zl[3]);
      *(uint2*)&bufA[icol * LSH + jb] = pz;
      *(uint2*)&bufB[icol * LSH + jb] = pl;
    }
  }
  __syncthreads();  // B4

  // ---- P3: OOt = M*Lt (ftab t=1, bufB=L) ; z_oo -> bufC (packed) ----
  f32x16 OOt;
#pragma unroll
  for (int r = 0; r < 16; ++r) OOt[r] = 0.0f;
#pragma unroll
  for (int kk = 0; kk < 4; ++kk) {
    const short8 a = *(const short8*)&ftab[((rb * 4 + kk) * 64 + lane) * 8];  // (gr,rb)
    const short8 b = ldrow(&bufB[(cb * 32 + l31) * LSH + kk * 16 + q * 8]);
    OOt = __builtin_amdgcn_mfma_f32_32x32x16_bf16(a, b, OOt, 0, 0, 0);
  }
  {
    const int icol = cb * 32 + l31;
#pragma unroll
    for (int k = 0; k < 4; ++k) {
      const int jb = rb * 32 + 4 * q + 8 * k;
      short zo[4];
#pragma unroll
      for (int t = 0; t < 4; ++t) {
        const int r = 4 * k + t;
        zo[t] = f2bf(OOt[r] * OOt[r]);
      }
      uint2 p;
      p.x = pk2(zo[0], zo[1]); p.y = pk2(zo[2], zo[3]);
      *(uint2*)&bufC[icol * LSH + jb] = p;  // z_oo[i][j]
    }
  }
  // pin: t=0 staging values materialized here (P2+P3 covered the L2 latency)
  asm volatile("" : "+v"(u0), "+v"(u1));
  __syncthreads();  // B5: all ftab t=1 reads done

  // ---- swap ftab to t=0 half ----
  {
    f32x4* fdst = (f32x4*)ftab;
    fdst[tid] = u0;
    fdst[tid + 256] = u1;
  }
  __syncthreads();  // B5b: ftab(t=0) published

  // ---- P4: Ut = z_oeT + M^T z_ooT ; W = z_eo*M ; U^T -> bufB ----
  f32x16 Ut, Wv;
#pragma unroll
  for (int r = 0; r < 16; ++r) { Ut[r] = zoe[r]; Wv[r] = 0.0f; }
#pragma unroll
  for (int kk = 0; kk < 4; ++kk) {
    const short8 aU = *(const short8*)&ftab[((rb * 4 + kk) * 64 + lane) * 8];  // (g,rb)
    const short8 bU = ldrow(&bufC[(cb * 32 + l31) * LSH + kk * 16 + q * 8]);
    Ut = __builtin_amdgcn_mfma_f32_32x32x16_bf16(aU, bU, Ut, 0, 0, 0);
    const short8 aW = ldrow(&bufA[(rb * 32 + l31) * LSH + kk * 16 + q * 8]);  // z_eo rows
    const short8 bW = *(const short8*)&ftab[((cb * 4 + kk) * 64 + lane) * 8];  // (g,cb)
    Wv = __builtin_amdgcn_mfma_f32_32x32x16_bf16(aW, bW, Wv, 0, 0, 0);
  }
#pragma unroll
  for (int r = 0; r < 16; ++r) {
    const int jrow = rb * 32 + (r & 3) + 4 * q + 8 * (r >> 2);
    const int icol = cb * 32 + l31;
    bufB[jrow * LSH + icol] = f2bf(Ut[r]);  // U^T row-major; strided, scalar
  }
  __syncthreads();  // B6

  // ---- P5: V = M^T U ; epilogue ----
  f32x16 Vv;
#pragma unroll
  for (int r = 0; r < 16; ++r) Vv[r] = 0.0f;
#pragma unroll
  for (int kk = 0; kk < 4; ++kk) {
    const short8 a = *(const short8*)&ftab[((rb * 4 + kk) * 64 + lane) * 8];  // (g,rb)
    const short8 b = ldrow(&bufB[(cb * 32 + l31) * LSH + kk * 16 + q * 8]);
    Vv = __builtin_amdgcn_mfma_f32_32x32x16_bf16(a, b, Vv, 0, 0, 0);
  }

  const float c0 = coef[0], c1 = coef[1];
  const float c2q = 0.25f * coef[2];
  float* ob = out + base;
  const float tv = tvec[jcol];   // hoisted: 1 read (was 16)
  const float sg = sigv;         // hoisted
  const float sgj = (jcol & 1) ? -1.0f : 1.0f;
#pragma unroll
  for (int k = 0; k < 4; ++k) {
    const int irowb = rb * 32 + 4 * q + 8 * k;  // irowb%4==0, even
    const f32x4 uv = *(const f32x4*)&uvec[irowb];  // one b128 for 4 rows
#pragma unroll
    for (int j = 0; j < 4; ++j) {
      const int r = 4 * k + j;
      const int irow = irowb + j;
      const float sgi = (j & 1) ? -1.0f : 1.0f;  // irowb even -> parity = j&1
      const float xv_ = bf2f(f2bf(xcur[r]));
      const float vee = xv_ + (sgi * tv + uv[j] * sgj) * (1.0f / 64.0f) +
                        sgi * sgj * sg * (1.0f / 4096.0f);
      const float zee = vee * vee;
      ob[irow * 64 + jcol] = c0 + c1 * xcur[r] + c2q * (zee + Vv[r] + Wv[r]);
    }
  }
}

extern "C" void kernel_launch(void* const* d_in, const int* in_sizes, int n_in,
                              void* d_out, int out_size, void* d_ws,
                              size_t ws_size, hipStream_t stream) {
  const float* x = (const float*)d_in[0];
  const float* coef = (const float*)d_in[1];
  float* out = (float*)d_out;
  const int channels = out_size / 4096;  // 32*128 channels of 64x64
  uppolyact_setup<<<dim3(1), dim3(256), 0, stream>>>();
  uppolyact_kernel<<<dim3(channels), dim3(256), 0, stream>>>(x, coef, out);
}

// Round 13
// 127.178 us; speedup vs baseline: 1.2828x; 1.2330x over previous
//
#include <hip/hip_runtime.h>
#include <math.h>

// UpPolyAct: out = c0 + c1*x + 0.25*c2*( z_ee + V + W )
//   R = X M^T, L = M X, OO = L M^T
//   z_eo=(R+corr)^2, z_oe=(L+corr)^2, z_oo=OO^2, z_ee=(E X E)^2
//   U = z_oe + z_oo M,  V = M^T U,  W = z_eo M
//
// R13 = R12 with ONE change: __launch_bounds__(256, 4) -> (256, 3).
// Evidence (R7/R11/R12): with bounds=4 the allocator hard-caps at 64 VGPR
// (8-waves/SIMD quantum) and SPILLS anything past it — R12's +86MB WRITE /
// +40MB FETCH was xcur[16] going to scratch when the epilogue's f32x4 temp
// pushed pressure past 64. bounds=3 raises the cap (~170); occupancy stays
// LDS-limited at 4 blocks/CU (35.8 KB) as long as actual VGPR <= 128.
// This is the clean test of the DS-issue-reduction theory (R12's cuts:
// P2 sRv f32x4 + Luv hoist, epilogue uvec f32x4 + tvec/sigv hoist).

typedef short short8 __attribute__((ext_vector_type(8)));
typedef float f32x16 __attribute__((ext_vector_type(16)));
typedef float f32x4 __attribute__((ext_vector_type(4)));

#define LSH 68  // bf16 LDS row stride (68 shorts = 136 B, rows 8B-aligned)

__device__ unsigned g_flag;                      // zero-initialized (.bss)
__device__ float g_gws[64];
__device__ __align__(16) short g_ftw[16 * 64 * 8];  // slot=(t*2+blk)*4+kk; t=0: [0,8KB), t=1: [8KB,16KB)

__device__ __forceinline__ short f2bf(float f) {
  unsigned u = __float_as_uint(f);
  u += 0x7FFFu + ((u >> 16) & 1u);
  return (short)(u >> 16);
}
__device__ __forceinline__ float bf2f(short s) {
  return __uint_as_float(((unsigned)(unsigned short)s) << 16);
}
__device__ __forceinline__ short8 ldrow(const short* p) {
  union { unsigned u[4]; short8 s; } v;
  const uint2 lo = *(const uint2*)p;
  const uint2 hi = *(const uint2*)(p + 4);
  v.u[0] = lo.x; v.u[1] = lo.y; v.u[2] = hi.x; v.u[3] = hi.y;
  return v.s;
}
__device__ __forceinline__ unsigned pk2(short a, short b) {
  return (unsigned)(unsigned short)a | ((unsigned)(unsigned short)b << 16);
}

// ---- setup: build g64 (64 f32) + ftab (16*64*8 bf16) into device globals ----
__global__ void uppolyact_setup() {
  if (g_flag == 0xC0FFEEu) return;  // replays early-out
  __shared__ float g64s[64];
  const int tid = threadIdx.x;
  if (tid < 64) {
    const int d = 2 * tid + 1;
    float s = 1.0f;
    for (int k = 1; k <= 32; ++k) {
      const int qq = (k * d) & 127;
      s += 2.0f * cosf((float)M_PI * (1.0f / 64.0f) * (float)qq);
    }
    const float gv = s * (1.0f / 64.0f);
    g64s[tid] = gv;
    g_gws[tid] = gv;
  }
  __syncthreads();
#pragma unroll
  for (int e = 0; e < 4; ++e) {
    const int entry = tid + 256 * e;  // 0..1023
    const int s_ = entry >> 6, ln = entry & 63;
    const int t_ = s_ >> 3, blk = (s_ >> 2) & 1, kk = s_ & 3;
    const int basei = kk * 16 + (ln >> 5) * 8 - (ln & 31) - 32 * blk;
    short* dst = &g_ftw[(s_ * 64 + ln) * 8];
#pragma unroll
    for (int j = 0; j < 8; ++j) {
      const int i0 = basei + j;
      const int idx = t_ ? ((-i0) & 63) : (i0 & 63);
      dst[j] = f2bf(g64s[idx]);
    }
  }
  __syncthreads();
  if (tid == 0) g_flag = 0xC0FFEEu;
}

__global__ __launch_bounds__(256, 3) void uppolyact_kernel(
    const float* __restrict__ x, const float* __restrict__ coef,
    float* __restrict__ out) {
  // bufA: X rows -> z_eo rows; bufB: X^T rows -> L rows -> U^T rows;
  // bufC: z_oo rows
  __shared__ __align__(16) short bufA[64 * LSH];
  __shared__ __align__(16) short bufB[64 * LSH];
  __shared__ __align__(16) short bufC[64 * LSH];
  __shared__ __align__(16) short ftab[8 * 64 * 8];  // time-shared: t=1 (gr) then t=0 (g)
  __shared__ __align__(16) float g64[64];
  __shared__ __align__(16) float tvec[64];
  __shared__ __align__(16) float uvec[64];
  __shared__ __align__(16) float sRv[64];
  __shared__ __align__(16) float Luv[64];
  __shared__ float sigv;

  const int tid = threadIdx.x;
  const int lane = tid & 63;
  const int w = tid >> 6;
  const int q = lane >> 5;
  const int l31 = lane & 31;
  const int rb = w >> 1, cb = w & 1;
  const int jcol = cb * 32 + l31;  // this thread's fixed output column
  const size_t base = (size_t)blockIdx.x * 4096;
  const float* xb = x + base;

  // ---- issue x loads FIRST (fragment order) ----
  float xcur[16];
#pragma unroll
  for (int r = 0; r < 16; ++r) {
    const int irow = rb * 32 + (r & 3) + 4 * q + 8 * (r >> 2);
    xcur[r] = xb[irow * 64 + jcol];
  }
  // ---- issue ftab t=1 (gr) copy loads: 8 KB, L2/L3-hot across all blocks
  f32x4 t0, t1;
  {
    const f32x4* fsrc = (const f32x4*)(g_ftw + 8 * 64 * 8);  // t=1 half
    t0 = fsrc[tid];
    t1 = fsrc[tid + 256];
  }
  if (tid < 64) g64[tid] = g_gws[tid];

  // ---- P0: xcur regs -> bufA (X rows, scalar) + bufB (X^T, packed b64) ----
#pragma unroll
  for (int k = 0; k < 4; ++k) {
    const int irowb = rb * 32 + 4 * q + 8 * k;  // irow = irowb + j, j=0..3
    short b[4];
#pragma unroll
    for (int j = 0; j < 4; ++j) {
      b[j] = f2bf(xcur[4 * k + j]);
      bufA[(irowb + j) * LSH + jcol] = b[j];
    }
    uint2 p;
    p.x = pk2(b[0], b[1]);
    p.y = pk2(b[2], b[3]);
    *(uint2*)&bufB[jcol * LSH + irowb] = p;
  }
  {
    f32x4* fdst = (f32x4*)ftab;
    fdst[tid] = t0;
    fdst[tid + 256] = t1;
  }
  __syncthreads();  // B1: g64 + bufA/bufB + ftab(t=1) published

  // ---- M1 tvec/uvec (all 256 threads, vectorized) ----
  {
    const int o = tid >> 1, h = tid & 1;  // o: output 0..127, h: half
    const short* src = (o < 64) ? &bufB[o * LSH + 32 * h]
                                : &bufA[(o - 64) * LSH + 32 * h];
    float acc = 0.0f;
#pragma unroll
    for (int p = 0; p < 4; ++p) {
      const short8 v = ldrow(src + 8 * p);
#pragma unroll
      for (int j = 0; j < 8; ++j) {
        const float f = bf2f(v[j]);
        acc += (j & 1) ? -f : f;
      }
    }
    acc += __shfl_xor(acc, 1);
    if (h == 0) {
      if (o < 64) tvec[o] = acc; else uvec[o - 64] = acc;
    }
  }
  __syncthreads();  // B2: tvec/uvec published

  // ---- Phase C: MFMA Rt, Lt (frags from ftab t=1) + M2 sRv/Luv + sigv ----
  f32x16 Rt, Lt;
#pragma unroll
  for (int r = 0; r < 16; ++r) { Rt[r] = 0.0f; Lt[r] = 0.0f; }
#pragma unroll
  for (int kk = 0; kk < 4; ++kk) {
    const short8 aR = *(const short8*)&ftab[((rb * 4 + kk) * 64 + lane) * 8];  // (gr,rb)
    const short8 bR = ldrow(&bufA[(cb * 32 + l31) * LSH + kk * 16 + q * 8]);
    Rt = __builtin_amdgcn_mfma_f32_32x32x16_bf16(aR, bR, Rt, 0, 0, 0);
    const short8 aL = ldrow(&bufB[(rb * 32 + l31) * LSH + kk * 16 + q * 8]);
    const short8 bL = *(const short8*)&ftab[((cb * 4 + kk) * 64 + lane) * 8];  // (gr,cb)
    Lt = __builtin_amdgcn_mfma_f32_32x32x16_bf16(aL, bL, Lt, 0, 0, 0);
  }
  {
    // sRv[o]=sum_m tvec[m]*g64[(o-m)&63] ; Luv[o]=sum_m g64[(o-m)&63]*uvec[m]
    const int o = tid >> 1, h = tid & 1;
    const int o63 = o & 63;
    const float* vsrc = (o < 64) ? tvec : uvec;  // wave-uniform select
    float acc = 0.0f;
#pragma unroll
    for (int p = 0; p < 32; ++p) {
      const int m = 32 * h + p;
      acc += vsrc[m] * g64[(o63 - m) & 63];
    }
    acc += __shfl_xor(acc, 1);
    if (h == 0) {
      if (o < 64) sRv[o] = acc; else Luv[o - 64] = acc;
    }
  }
  if (w == 0) {  // sigv = s^T X s
    float sv = (lane & 1) ? -tvec[lane] : tvec[lane];
#pragma unroll
    for (int d_ = 1; d_ < 64; d_ <<= 1) sv += __shfl_xor(sv, d_);
    if (lane == 0) sigv = sv;
  }
  __syncthreads();  // B3

  // ---- P2: issue ftab t=0 loads; z_eoT -> bufA, Lt -> bufB (packed) ----
  f32x4 u0, u1;
  {
    const f32x4* fsrc = (const f32x4*)g_ftw;  // t=0 half
    u0 = fsrc[tid];
    u1 = fsrc[tid + 256];
  }
  float zoe[16];
  {
    const int icol = cb * 32 + l31;
    const float sgi = (icol & 1) ? -1.0f : 1.0f;
    const float lu = Luv[icol];  // hoisted: 1 read (was 16)
#pragma unroll
    for (int k = 0; k < 4; ++k) {
      const int jb = rb * 32 + 4 * q + 8 * k;  // jb%4==0 -> 16B-aligned
      const f32x4 sr = *(const f32x4*)&sRv[jb];  // 4 sRv in one b128
      short ze[4], zl[4];
#pragma unroll
      for (int t = 0; t < 4; ++t) {
        const int r = 4 * k + t;
        const int jrow = jb + t;
        const float sgj = (jrow & 1) ? -1.0f : 1.0f;
        const float veo = Rt[r] + sgi * sr[t] * (1.0f / 64.0f);
        ze[t] = f2bf(veo * veo);               // z_eo[i][j]
        zl[t] = f2bf(Lt[r]);                   // L[i][j]
        const float voe = Lt[r] + lu * sgj * (1.0f / 64.0f);
        zoe[r] = voe * voe;                    // z_oeT[j][i] (C-layout)
      }
      uint2 pz, pl;
      pz.x = pk2(ze[0], ze[1]); pz.y = pk2(ze[2], ze[3]);
      pl.x = pk2(zl[0], zl[1]); pl.y = pk2(zl[2], zl[3]);
      *(uint2*)&bufA[icol * LSH + jb] = pz;
      *(uint2*)&bufB[icol * LSH + jb] = pl;
    }
  }
  __syncthreads();  // B4

  // ---- P3: OOt = M*Lt (ftab t=1, bufB=L) ; z_oo -> bufC (packed) ----
  f32x16 OOt;
#pragma unroll
  for (int r = 0; r < 16; ++r) OOt[r] = 0.0f;
#pragma unroll
  for (int kk = 0; kk < 4; ++kk) {
    const short8 a = *(const short8*)&ftab[((rb * 4 + kk) * 64 + lane) * 8];  // (gr,rb)
    const short8 b = ldrow(&bufB[(cb * 32 + l31) * LSH + kk * 16 + q * 8]);
    OOt = __builtin_amdgcn_mfma_f32_32x32x16_bf16(a, b, OOt, 0, 0, 0);
  }
  {
    const int icol = cb * 32 + l31;
#pragma unroll
    for (int k = 0; k < 4; ++k) {
      const int jb = rb * 32 + 4 * q + 8 * k;
      short zo[4];
#pragma unroll
      for (int t = 0; t < 4; ++t) {
        const int r = 4 * k + t;
        zo[t] = f2bf(OOt[r] * OOt[r]);
      }
      uint2 p;
      p.x = pk2(zo[0], zo[1]); p.y = pk2(zo[2], zo[3]);
      *(uint2*)&bufC[icol * LSH + jb] = p;  // z_oo[i][j]
    }
  }
  // pin: t=0 staging values materialized here (P2+P3 covered the L2 latency)
  asm volatile("" : "+v"(u0), "+v"(u1));
  __syncthreads();  // B5: all ftab t=1 reads done

  // ---- swap ftab to t=0 half ----
  {
    f32x4* fdst = (f32x4*)ftab;
    fdst[tid] = u0;
    fdst[tid + 256] = u1;
  }
  __syncthreads();  // B5b: ftab(t=0) published

  // ---- P4: Ut = z_oeT + M^T z_ooT ; W = z_eo*M ; U^T -> bufB ----
  f32x16 Ut, Wv;
#pragma unroll
  for (int r = 0; r < 16; ++r) { Ut[r] = zoe[r]; Wv[r] = 0.0f; }
#pragma unroll
  for (int kk = 0; kk < 4; ++kk) {
    const short8 aU = *(const short8*)&ftab[((rb * 4 + kk) * 64 + lane) * 8];  // (g,rb)
    const short8 bU = ldrow(&bufC[(cb * 32 + l31) * LSH + kk * 16 + q * 8]);
    Ut = __builtin_amdgcn_mfma_f32_32x32x16_bf16(aU, bU, Ut, 0, 0, 0);
    const short8 aW = ldrow(&bufA[(rb * 32 + l31) * LSH + kk * 16 + q * 8]);  // z_eo rows
    const short8 bW = *(const short8*)&ftab[((cb * 4 + kk) * 64 + lane) * 8];  // (g,cb)
    Wv = __builtin_amdgcn_mfma_f32_32x32x16_bf16(aW, bW, Wv, 0, 0, 0);
  }
#pragma unroll
  for (int r = 0; r < 16; ++r) {
    const int jrow = rb * 32 + (r & 3) + 4 * q + 8 * (r >> 2);
    const int icol = cb * 32 + l31;
    bufB[jrow * LSH + icol] = f2bf(Ut[r]);  // U^T row-major; strided, scalar
  }
  __syncthreads();  // B6

  // ---- P5: V = M^T U ; epilogue ----
  f32x16 Vv;
#pragma unroll
  for (int r = 0; r < 16; ++r) Vv[r] = 0.0f;
#pragma unroll
  for (int kk = 0; kk < 4; ++kk) {
    const short8 a = *(const short8*)&ftab[((rb * 4 + kk) * 64 + lane) * 8];  // (g,rb)
    const short8 b = ldrow(&bufB[(cb * 32 + l31) * LSH + kk * 16 + q * 8]);
    Vv = __builtin_amdgcn_mfma_f32_32x32x16_bf16(a, b, Vv, 0, 0, 0);
  }

  const float c0 = coef[0], c1 = coef[1];
  const float c2q = 0.25f * coef[2];
  float* ob = out + base;
  const float tv = tvec[jcol];   // hoisted: 1 read (was 16)
  const float sg = sigv;         // hoisted
  const float sgj = (jcol & 1) ? -1.0f : 1.0f;
#pragma unroll
  for (int k = 0; k < 4; ++k) {
    const int irowb = rb * 32 + 4 * q + 8 * k;  // irowb%4==0, even
    const f32x4 uv = *(const f32x4*)&uvec[irowb];  // one b128 for 4 rows
#pragma unroll
    for (int j = 0; j < 4; ++j) {
      const int r = 4 * k + j;
      const int irow = irowb + j;
      const float sgi = (j & 1) ? -1.0f : 1.0f;  // irowb even -> parity = j&1
      const float xv_ = bf2f(f2bf(xcur[r]));
      const float vee = xv_ + (sgi * tv + uv[j] * sgj) * (1.0f / 64.0f) +
                        sgi * sgj * sg * (1.0f / 4096.0f);
      const float zee = vee * vee;
      ob[irow * 64 + jcol] = c0 + c1 * xcur[r] + c2q * (zee + Vv[r] + Wv[r]);
    }
  }
}

extern "C" void kernel_launch(void* const* d_in, const int* in_sizes, int n_in,
                              void* d_out, int out_size, void* d_ws,
                              size_t ws_size, hipStream_t stream) {
  const float* x = (const float*)d_in[0];
  const float* coef = (const float*)d_in[1];
  float* out = (float*)d_out;
  const int channels = out_size / 4096;  // 32*128 channels of 64x64
  uppolyact_setup<<<dim3(1), dim3(256), 0, stream>>>();
  uppolyact_kernel<<<dim3(channels), dim3(256), 0, stream>>>(x, coef, out);
}